// Round 9
// baseline (267.612 us; speedup 1.0000x reference)
//
#include <hip/hip_runtime.h>
#include <cfloat>
#include <cmath>

// Problem constants
#define SN 8
#define DN 64
#define KN 512
#define NN 16384            // B*T
#define CK 64               // K-chunk (loop tiling only; no LDS staging)
#define REPAIR_THR 2e-3f    // float-path flag threshold (fallback kernel)
#define GAP_IK 4u           // packed-int flag: 4/4096 = 9.8e-4 in d2 units
#define MAXFLAG 32768

// workspace layout (float indices)
#define WS_CNT 0
#define WS_SCL 16
#define WS_OFF (16 + SN*DN)           // 528
#define WS_E2  (WS_OFF + SN*DN)       // 1040
#define WS_ENT (WS_E2 + SN*KN)        // 5136
#define WS_WTH (WS_ENT + MAXFLAG)     // 37904 : W^T hi bf16 image (SN*64*128 B, UNswizzled)
#define WS_WTL (WS_WTH + SN*64*32)    // 54288
#define WS_EH  (WS_WTL + SN*64*32)    // 70672 : E hi bf16 image (SN*KN*128 B, UNswizzled)
#define WS_EL  (WS_EH + SN*KN*32)     // 201744
#define WS_ZP  (WS_EL + SN*KN*32)     // 332816: z partials [S][N][D] fp32
#define WS_E2S (WS_ZP + SN*NN*DN)     // 8721424: 4096*||E||^2 (phase-D scaled)
#define WS_END (WS_E2S + SN*KN)       // 8725520 floats = 34.9 MB

// main LDS (512-thread / 128-row tile): Z hi 16K, Z lo 16K (no E staging)
#define LDS_ZH 0
#define LDS_ZL 16384
#define LDS_TOTAL 32768               // 4 blocks/CU = 32 waves/CU (thread-capped)

// fallback (round-2 proven) LDS
#define FB_LDS_R2    17408
#define FB_LDS_TAIL  33792
#define FB_LDS_TOTAL 34816

typedef __attribute__((ext_vector_type(8))) short bf16x8;   // 8 bf16 = 4 VGPR
typedef __attribute__((ext_vector_type(4))) short s16x4;    // 8 B
typedef __attribute__((ext_vector_type(4))) float f32x4;    // MFMA acc

// float -> bf16(RTNE) hi + remainder
__device__ inline short bf_hi(float f, float& rem) {
    unsigned u = __float_as_uint(f);
    unsigned r = (u + 0x7fffu + ((u >> 16) & 1u)) & 0xffff0000u;
    rem = f - __uint_as_float(r);
    return (short)(r >> 16);
}
__device__ inline short bf_rn(float f) {
    unsigned u = __float_as_uint(f);
    return (short)((u + 0x7fffu + ((u >> 16) & 1u)) >> 16);
}
__device__ inline void cvt4(float a, float b, float c, float d, s16x4& h, s16x4& l) {
    float r0, r1, r2, r3;
    h.x = bf_hi(a, r0); h.y = bf_hi(b, r1); h.z = bf_hi(c, r2); h.w = bf_hi(d, r3);
    l.x = bf_rn(r0); l.y = bf_rn(r1); l.z = bf_rn(r2); l.w = bf_rn(r3);
}
__device__ inline float bf2f(unsigned short h) {
    return __uint_as_float(((unsigned)h) << 16);
}

union U8 { bf16x8 v; s16x4 q[2]; };

// ------------------------------------------------------------- prep_all -----
// One launch: blocks 0..255 E->hi/lo image (UNswizzled); 256..263 W^T image;
// 264..281 E2 (raw + 4096-scaled), BN fold, and flag-counter zeroing.
__global__ void prep_all_kernel(const float* __restrict__ b, const float* __restrict__ gamma,
                                const float* __restrict__ beta, const float* __restrict__ bmean,
                                const float* __restrict__ bvar, const float* __restrict__ W,
                                const float* __restrict__ E, float* __restrict__ ws) {
    __shared__ float wt[64][65];
    const int blk = blockIdx.x, tid = threadIdx.x;
    if (blk < 256) {                           // E image (linear rows, no swizzle)
        int idx = blk * 256 + tid;             // SN*KN*16 = 65536
        int sk = idx >> 4, c4 = idx & 15;
        float4 g = ((const float4*)E)[(size_t)sk * 16 + c4];
        s16x4 h4, l4;
        cvt4(g.x, g.y, g.z, g.w, h4, l4);
        size_t off = (size_t)sk * 128 + c4 * 8;
        *(s16x4*)((char*)(ws + WS_EH) + off) = h4;
        *(s16x4*)((char*)(ws + WS_EL) + off) = l4;
    } else if (blk < 264) {                    // W^T image (UNswizzled)
        int s = blk - 256;
        #pragma unroll
        for (int r = 0; r < 4; ++r) {
            int i = r * 256 + tid;             // 1024 f4
            float4 g = ((const float4*)W)[(size_t)s * 1024 + i];
            int d = i >> 4, c4 = i & 15;
            wt[d][c4 * 4 + 0] = g.x; wt[d][c4 * 4 + 1] = g.y;
            wt[d][c4 * 4 + 2] = g.z; wt[d][c4 * 4 + 3] = g.w;
        }
        __syncthreads();
        #pragma unroll
        for (int r = 0; r < 4; ++r) {
            int j = r * 256 + tid;             // 64 e x 16 c4
            int e = j >> 4, c4 = j & 15;
            s16x4 h4, l4;
            cvt4(wt[c4 * 4 + 0][e], wt[c4 * 4 + 1][e], wt[c4 * 4 + 2][e], wt[c4 * 4 + 3][e], h4, l4);
            size_t off = (size_t)(s * 64 + e) * 128 + c4 * 8;
            *(s16x4*)((char*)(ws + WS_WTH) + off) = h4;
            *(s16x4*)((char*)(ws + WS_WTL) + off) = l4;
        }
    } else {                                   // E2 + BN fold + counter zero
        if (blk == 264 && tid < 16) ((int*)ws)[tid] = 0;
        int t2 = (blk - 264) * 256 + tid;
        if (t2 < SN * KN) {
            const float* er = E + (size_t)t2 * DN;
            double a = 0.0;
            for (int d = 0; d < DN; ++d) { double v = (double)er[d]; a = fma(v, v, a); }
            ws[WS_E2 + t2]  = (float)a;
            ws[WS_E2S + t2] = (float)(a * 4096.0);
        }
        int u = t2 - SN * KN;
        if (u >= 0 && u < SN * DN) {
            double inv = 1.0 / sqrt((double)bvar[u] + 0.001);
            double sc  = (double)gamma[u] * inv;
            ws[WS_SCL + u] = (float)sc;
            ws[WS_OFF + u] = (float)(((double)b[u] - (double)bmean[u]) * sc + (double)beta[u]);
        }
    }
}

// --------------------------------------------------- fallback-path prep -----
__global__ void prep_kernel(const float* __restrict__ b, const float* __restrict__ gamma,
                            const float* __restrict__ beta, const float* __restrict__ bmean,
                            const float* __restrict__ bvar, const float* __restrict__ E,
                            float* __restrict__ ws) {
    int tid = blockIdx.x * 256 + threadIdx.x;
    if (tid < SN * KN) {
        const float* er = E + (size_t)tid * DN;
        double a = 0.0;
        for (int d = 0; d < DN; ++d) { double v = (double)er[d]; a = fma(v, v, a); }
        ws[WS_E2 + tid] = (float)a;
    }
    int u = tid - SN * KN;
    if (u >= 0 && u < SN * DN) {
        double inv = 1.0 / sqrt((double)bvar[u] + 0.001);
        double sc  = (double)gamma[u] * inv;
        ws[WS_SCL + u] = (float)sc;
        ws[WS_OFF + u] = (float)(((double)b[u] - (double)bmean[u]) * sc + (double)beta[u]);
    }
}

// ---------------------------------------------------------------- main ------
// grid: (128 tiles x 128 rows, 8 s). block: 512 threads (8 waves); wave w
// owns rows [16w,16w+16). ALL matrix operands register-direct from L2-hot
// images (W^T and E, unswizzled); Z transposed through LDS once. NO barriers
// in the k-loop -> waves free-run, pipes overlap. Argmin via packed u32 keys:
// key = (u32)((d2+16)*4096) << 9 | k.
__launch_bounds__(512, 8)
__global__ void main_kernel(const float* __restrict__ x, float* __restrict__ ws,
                            float* __restrict__ out, int entcap) {
    extern __shared__ char smraw[];
    const int tid = threadIdx.x;           // 0..511
    const int s  = blockIdx.y;
    const int n0 = blockIdx.x * 128;
    const int lane = tid & 63;
    const int w    = tid >> 6;             // 0..7
    const int cc   = lane & 15;
    const int kq   = lane >> 4;
    const int arow = w * 16 + cc;          // 0..127
    const int axor = (arow & 7) << 4;

    const char* eimg_h = (const char*)(ws + WS_EH) + (size_t)s * KN * 128;
    const char* eimg_l = (const char*)(ws + WS_EL) + (size_t)s * KN * 128;

    // ---- A-fragments (x rows) built in registers ----
    U8 xah[2], xal[2];
    #pragma unroll
    for (int ks = 0; ks < 2; ++ks) {
        const float* xr = x + (size_t)(n0 + arow) * DN + ks * 32 + kq * 8;
        float4 a = *(const float4*)xr;
        float4 b2 = *(const float4*)(xr + 4);
        s16x4 h0, l0, h1, l1;
        cvt4(a.x, a.y, a.z, a.w, h0, l0);
        cvt4(b2.x, b2.y, b2.z, b2.w, h1, l1);
        xah[ks].q[0] = h0; xah[ks].q[1] = h1;
        xal[ks].q[0] = l0; xal[ks].q[1] = l1;
    }

    // ---- phase C: proj = x @ W via MFMA, W^T frags register-direct ----
    const char* wimg_h = (const char*)(ws + WS_WTH) + (size_t)s * 64 * 128;
    const char* wimg_l = (const char*)(ws + WS_WTL) + (size_t)s * 64 * 128;
    f32x4 pa[4];
    #pragma unroll
    for (int nt = 0; nt < 4; ++nt) pa[nt] = (f32x4){0.f, 0.f, 0.f, 0.f};
    #pragma unroll
    for (int ks = 0; ks < 2; ++ks) {
        #pragma unroll
        for (int nt = 0; nt < 4; ++nt) {
            int brow = nt * 16 + cc;
            bf16x8 bh = *(const bf16x8*)(wimg_h + brow * 128 + ks * 64 + kq * 16);
            bf16x8 bl = *(const bf16x8*)(wimg_l + brow * 128 + ks * 64 + kq * 16);
            pa[nt] = __builtin_amdgcn_mfma_f32_16x16x32_bf16(xah[ks].v, bh, pa[nt], 0, 0, 0);
            pa[nt] = __builtin_amdgcn_mfma_f32_16x16x32_bf16(xah[ks].v, bl, pa[nt], 0, 0, 0);
            pa[nt] = __builtin_amdgcn_mfma_f32_16x16x32_bf16(xal[ks].v, bh, pa[nt], 0, 0, 0);
        }
    }

    // ---- BN + softmax + z (C/D layout: e = nt*16+cc, row = w*16+kq*4+r) ----
    float sclv[4], oflv[4];
    #pragma unroll
    for (int nt = 0; nt < 4; ++nt) {
        sclv[nt] = ws[WS_SCL + s * 64 + nt * 16 + cc];
        oflv[nt] = ws[WS_OFF + s * 64 + nt * 16 + cc];
    }
    float zzq[4];                      // (zz + 16) * 4096 per owned row
    #pragma unroll
    for (int r = 0; r < 4; ++r) {
        int t = w * 16 + kq * 4 + r;
        float v0 = fmaf(pa[0][r], sclv[0], oflv[0]);
        float v1 = fmaf(pa[1][r], sclv[1], oflv[1]);
        float v2 = fmaf(pa[2][r], sclv[2], oflv[2]);
        float v3 = fmaf(pa[3][r], sclv[3], oflv[3]);
        float mx = fmaxf(fmaxf(v0, v1), fmaxf(v2, v3));
        mx = fmaxf(mx, __shfl_xor(mx, 1)); mx = fmaxf(mx, __shfl_xor(mx, 2));
        mx = fmaxf(mx, __shfl_xor(mx, 4)); mx = fmaxf(mx, __shfl_xor(mx, 8));
        float e0 = __expf(v0 - mx), e1 = __expf(v1 - mx);
        float e2v = __expf(v2 - mx), e3 = __expf(v3 - mx);
        float sm = e0 + e1 + e2v + e3;
        sm += __shfl_xor(sm, 1); sm += __shfl_xor(sm, 2);
        sm += __shfl_xor(sm, 4); sm += __shfl_xor(sm, 8);
        float inv = 1.0f / sm;
        float att[4] = { e0 * inv, e1 * inv, e2v * inv, e3 * inv };
        float zz = 0.f;
        int txor = (t & 7) << 4;
        #pragma unroll
        for (int nt = 0; nt < 4; ++nt) {
            int e = nt * 16 + cc;
            float xv = x[(size_t)(n0 + t) * DN + e];     // exact fp32 x
            float z = xv * att[nt];
            zz += z * z;
            float rem; short zh = bf_hi(z, rem); short zl = bf_rn(rem);
            int zoff = (t * 128 + e * 2) ^ txor;
            *(short*)(smraw + LDS_ZH + zoff) = zh;
            *(short*)(smraw + LDS_ZL + zoff) = zl;
        }
        zz += __shfl_xor(zz, 1); zz += __shfl_xor(zz, 2);
        zz += __shfl_xor(zz, 4); zz += __shfl_xor(zz, 8);
        zzq[r] = (zz + 16.f) * 4096.f;
    }

    // hoist z fragments (own rows, intra-wave LDS -> no barrier needed)
    bf16x8 zah[2], zal[2];
    #pragma unroll
    for (int ks = 0; ks < 2; ++ks) {
        int aoff = (arow * 128 + kq * 16 + ks * 64) ^ axor;
        zah[ks] = *(const bf16x8*)(smraw + LDS_ZH + aoff);
        zal[ks] = *(const bf16x8*)(smraw + LDS_ZL + aoff);
    }
    __syncthreads();                   // publish Z block-wide for the transpose

    // ---- ZP store: coalesced float4 via LDS transpose (z = hi + lo) ----
    #pragma unroll
    for (int j = 0; j < 4; ++j) {
        int a = tid + j * 512;             // 128 rows x 16 e-quads
        int t = a >> 4, q = a & 15;
        int off = (t * 128 + q * 8) ^ ((t & 7) << 4);
        s16x4 h = *(const s16x4*)(smraw + LDS_ZH + off);
        s16x4 l = *(const s16x4*)(smraw + LDS_ZL + off);
        float4 zv;
        zv.x = bf2f((unsigned short)h.x) + bf2f((unsigned short)l.x);
        zv.y = bf2f((unsigned short)h.y) + bf2f((unsigned short)l.y);
        zv.z = bf2f((unsigned short)h.z) + bf2f((unsigned short)l.z);
        zv.w = bf2f((unsigned short)h.w) + bf2f((unsigned short)l.w);
        ((float4*)(ws + WS_ZP))[((size_t)s * NN + n0 + t) * 16 + q] = zv;
    }

    // ---- phase D: z @ E^T via MFMA, E frags register-direct from L2 ----
    unsigned m1[4], m2[4];
    #pragma unroll
    for (int r = 0; r < 4; ++r) { m1[r] = 0xFFFFFFFFu; m2[r] = 0xFFFFFFFFu; }

    #pragma unroll 1
    for (int c = 0; c < KN / CK; ++c) {
        int kk = c * CK;
        float e2v[4];                                    // pre-scaled 4096*e2
        #pragma unroll
        for (int nt = 0; nt < 4; ++nt) e2v[nt] = ws[WS_E2S + s * KN + kk + nt * 16 + cc];

        f32x4 acc[4];
        #pragma unroll
        for (int nt = 0; nt < 4; ++nt) acc[nt] = (f32x4){0.f, 0.f, 0.f, 0.f};
        #pragma unroll
        for (int ks = 0; ks < 2; ++ks) {
            #pragma unroll
            for (int nt = 0; nt < 4; ++nt) {
                size_t boff = (size_t)(kk + nt * 16 + cc) * 128 + ks * 64 + kq * 16;
                bf16x8 bh = *(const bf16x8*)(eimg_h + boff);
                bf16x8 bl = *(const bf16x8*)(eimg_l + boff);
                acc[nt] = __builtin_amdgcn_mfma_f32_16x16x32_bf16(zah[ks], bh, acc[nt], 0, 0, 0);
                acc[nt] = __builtin_amdgcn_mfma_f32_16x16x32_bf16(zah[ks], bl, acc[nt], 0, 0, 0);
                acc[nt] = __builtin_amdgcn_mfma_f32_16x16x32_bf16(zal[ks], bh, acc[nt], 0, 0, 0);
            }
        }
        #pragma unroll
        for (int nt = 0; nt < 4; ++nt) {
            unsigned kx = (unsigned)(kk + nt * 16 + cc);
            #pragma unroll
            for (int r = 0; r < 4; ++r) {
                // cell = 4096*(d2+16) in [0, ~2^21) -> cvt exact, no clamp
                float cell = fmaf(-8192.f, acc[nt][r], zzq[r] + e2v[nt]);
                unsigned key = (((unsigned)cell) << 9) | kx;
                m2[r] = min(m2[r], max(m1[r], key));
                m1[r] = min(m1[r], key);
            }
        }
    }

    // cross-lane (16 lanes = distinct k) merge; k-tiebreak free in key space
    #pragma unroll
    for (int mask = 1; mask <= 8; mask <<= 1) {
        #pragma unroll
        for (int r = 0; r < 4; ++r) {
            unsigned o1 = (unsigned)__shfl_xor((int)m1[r], mask);
            unsigned o2 = (unsigned)__shfl_xor((int)m2[r], mask);
            unsigned hi = max(m1[r], o1);
            m1[r] = min(m1[r], o1);
            m2[r] = min(min(m2[r], o2), hi);
        }
    }
    #pragma unroll
    for (int r = 0; r < 4; ++r) {
        int n = n0 + w * 16 + kq * 4 + r;
        if (cc == 0) {
            int k1 = (int)(m1[r] & 511u);
            out[2 * NN * DN + s * NN + n] = (float)k1;
            if ((m2[r] >> 9) - (m1[r] >> 9) <= GAP_IK) {   // near-tie -> fp64 repair
                int idx = atomicAdd((int*)ws, 1);
                if (idx < entcap) ((int*)ws)[WS_ENT + idx] = (s << 14) | n;
            }
        }
    }
}

// ----------------------------------------------------- fallback main --------
// Round-2-proven path for small workspaces: fp32 phase C, in-kernel E cvt,
// atomic zq/ze accumulation. Needs only WS_ENT region.
__launch_bounds__(256, 4)
__global__ void main_fb_kernel(const float* __restrict__ x, const float* __restrict__ W,
                               const float* __restrict__ E, float* __restrict__ ws,
                               float* __restrict__ out, int entcap) {
    extern __shared__ char smraw[];
    float4* xs4 = (float4*)smraw;
    float4* ws4 = (float4*)(smraw + FB_LDS_R2);
    char* ehb = smraw;
    char* elb = smraw + 8192;
    char* zhb = smraw + FB_LDS_R2;
    char* zlb = smraw + FB_LDS_R2 + 8192;
    float* tailf = (float*)(smraw + FB_LDS_TAIL);
    float* e2s = tailf; float* scl = tailf + 64; float* ofl = tailf + 128; float* zzs = tailf + 192;

    const int tid = threadIdx.x;
    const int tg = tid >> 4, lg = tid & 15;
    const int s  = blockIdx.y;
    const int n0 = blockIdx.x * 64;
    const float4* xg4 = (const float4*)x;
    const float4* Wg4 = (const float4*)W;
    const float4* Eg4 = (const float4*)E;

    #pragma unroll
    for (int r = 0; r < 4; ++r) {
        int i = r * 256 + tid;
        xs4[(i >> 4) * 17 + (i & 15)] = xg4[n0 * 16 + i];
        ws4[i] = Wg4[s * 1024 + i];
    }
    if (tid < 64) { scl[tid] = ws[WS_SCL + s * 64 + tid]; ofl[tid] = ws[WS_OFF + s * 64 + tid]; }
    __syncthreads();

    float pa[4][4];
    #pragma unroll
    for (int ti = 0; ti < 4; ++ti)
        #pragma unroll
        for (int j = 0; j < 4; ++j) pa[ti][j] = 0.f;
    #pragma unroll 4
    for (int c = 0; c < 16; ++c) {
        float4 xv[4], wv[4];
        #pragma unroll
        for (int ti = 0; ti < 4; ++ti) xv[ti] = xs4[(tg * 4 + ti) * 17 + c];
        #pragma unroll
        for (int dd = 0; dd < 4; ++dd) wv[dd] = ws4[(c * 4 + dd) * 16 + lg];
        #pragma unroll
        for (int ti = 0; ti < 4; ++ti) {
            float a0 = pa[ti][0], a1 = pa[ti][1], a2 = pa[ti][2], a3 = pa[ti][3];
            a0 = fmaf(xv[ti].x, wv[0].x, a0); a0 = fmaf(xv[ti].y, wv[1].x, a0);
            a0 = fmaf(xv[ti].z, wv[2].x, a0); a0 = fmaf(xv[ti].w, wv[3].x, a0);
            a1 = fmaf(xv[ti].x, wv[0].y, a1); a1 = fmaf(xv[ti].y, wv[1].y, a1);
            a1 = fmaf(xv[ti].z, wv[2].y, a1); a1 = fmaf(xv[ti].w, wv[3].y, a1);
            a2 = fmaf(xv[ti].x, wv[0].z, a2); a2 = fmaf(xv[ti].y, wv[1].z, a2);
            a2 = fmaf(xv[ti].z, wv[2].z, a2); a2 = fmaf(xv[ti].w, wv[3].z, a2);
            a3 = fmaf(xv[ti].x, wv[0].w, a3); a3 = fmaf(xv[ti].y, wv[1].w, a3);
            a3 = fmaf(xv[ti].z, wv[2].w, a3); a3 = fmaf(xv[ti].w, wv[3].w, a3);
            pa[ti][0] = a0; pa[ti][1] = a1; pa[ti][2] = a2; pa[ti][3] = a3;
        }
    }
    __syncthreads();

    {
        float s0 = scl[lg * 4 + 0], s1 = scl[lg * 4 + 1], s2 = scl[lg * 4 + 2], s3 = scl[lg * 4 + 3];
        float o0 = ofl[lg * 4 + 0], o1 = ofl[lg * 4 + 1], o2 = ofl[lg * 4 + 2], o3 = ofl[lg * 4 + 3];
        #pragma unroll
        for (int ti = 0; ti < 4; ++ti) {
            int t = tg * 4 + ti;
            float v0 = fmaf(pa[ti][0], s0, o0);
            float v1 = fmaf(pa[ti][1], s1, o1);
            float v2 = fmaf(pa[ti][2], s2, o2);
            float v3 = fmaf(pa[ti][3], s3, o3);
            float mx = fmaxf(fmaxf(v0, v1), fmaxf(v2, v3));
            mx = fmaxf(mx, __shfl_xor(mx, 1)); mx = fmaxf(mx, __shfl_xor(mx, 2));
            mx = fmaxf(mx, __shfl_xor(mx, 4)); mx = fmaxf(mx, __shfl_xor(mx, 8));
            float e0 = expf(v0 - mx), e1 = expf(v1 - mx), e2v = expf(v2 - mx), e3 = expf(v3 - mx);
            float sm = e0 + e1 + e2v + e3;
            sm += __shfl_xor(sm, 1); sm += __shfl_xor(sm, 2);
            sm += __shfl_xor(sm, 4); sm += __shfl_xor(sm, 8);
            float inv = 1.0f / sm;
            float4 xv = xs4[t * 17 + lg];
            float z0 = xv.x * (e0 * inv), z1 = xv.y * (e1 * inv);
            float z2 = xv.z * (e2v * inv), z3 = xv.w * (e3 * inv);
            float zz = z0 * z0 + z1 * z1 + z2 * z2 + z3 * z3;
            zz += __shfl_xor(zz, 1); zz += __shfl_xor(zz, 2);
            zz += __shfl_xor(zz, 4); zz += __shfl_xor(zz, 8);
            if (lg == 0) zzs[t] = zz;
            s16x4 h4, l4;
            cvt4(z0, z1, z2, z3, h4, l4);
            int zoff = (t * 128 + lg * 8) ^ ((t & 7) << 4);
            *(s16x4*)(zhb + zoff) = h4;
            *(s16x4*)(zlb + zoff) = l4;
            float* pz = out + NN * DN + (size_t)(n0 + t) * DN + lg * 4;
            atomicAdd(pz + 0, z0); atomicAdd(pz + 1, z1);
            atomicAdd(pz + 2, z2); atomicAdd(pz + 3, z3);
        }
    }
    __syncthreads();

    const int lane = tid & 63;
    const int w    = tid >> 6;
    const int arow = w * 16 + (lane & 15);
    const int kg16 = (lane >> 4) * 16;
    const int axor = (arow & 7) << 4;
    const int abase = arow * 128 + kg16;

    float zzv[4];
    #pragma unroll
    for (int r = 0; r < 4; ++r) zzv[r] = zzs[w * 16 + (lane >> 4) * 4 + r];

    float m1[4], m2[4]; int k1[4];
    #pragma unroll
    for (int r = 0; r < 4; ++r) { m1[r] = FLT_MAX; m2[r] = FLT_MAX; k1[r] = 0x7fffffff; }

    for (int kk = 0; kk < KN; kk += CK) {
        __syncthreads();
        #pragma unroll
        for (int r = 0; r < 4; ++r) {
            int i = r * 256 + tid;
            float4 g = Eg4[(s * KN + kk) * 16 + i];
            int row = i >> 4, c4 = i & 15;
            s16x4 h4, l4;
            cvt4(g.x, g.y, g.z, g.w, h4, l4);
            int off = (row * 128 + c4 * 8) ^ ((row & 7) << 4);
            *(s16x4*)(ehb + off) = h4;
            *(s16x4*)(elb + off) = l4;
        }
        if (tid < 64) e2s[tid] = ws[WS_E2 + s * KN + kk + tid];
        __syncthreads();

        f32x4 acc[4];
        #pragma unroll
        for (int nt = 0; nt < 4; ++nt) acc[nt] = (f32x4){0.f, 0.f, 0.f, 0.f};
        #pragma unroll
        for (int ks = 0; ks < 2; ++ks) {
            int aoff = (abase + ks * 64) ^ axor;
            bf16x8 ah = *(const bf16x8*)(zhb + aoff);
            bf16x8 al = *(const bf16x8*)(zlb + aoff);
            #pragma unroll
            for (int nt = 0; nt < 4; ++nt) {
                int brow = nt * 16 + (lane & 15);
                int boff = (brow * 128 + kg16 + ks * 64) ^ ((brow & 7) << 4);
                bf16x8 bh = *(const bf16x8*)(ehb + boff);
                bf16x8 bl = *(const bf16x8*)(elb + boff);
                acc[nt] = __builtin_amdgcn_mfma_f32_16x16x32_bf16(ah, bh, acc[nt], 0, 0, 0);
                acc[nt] = __builtin_amdgcn_mfma_f32_16x16x32_bf16(ah, bl, acc[nt], 0, 0, 0);
                acc[nt] = __builtin_amdgcn_mfma_f32_16x16x32_bf16(al, bh, acc[nt], 0, 0, 0);
            }
        }
        #pragma unroll
        for (int nt = 0; nt < 4; ++nt) {
            float e2v = e2s[nt * 16 + (lane & 15)];
            int kx = kk + nt * 16 + (lane & 15);
            #pragma unroll
            for (int r = 0; r < 4; ++r) {
                float d2 = fmaf(-2.0f, acc[nt][r], zzv[r]) + e2v;
                if (d2 < m1[r]) { m2[r] = m1[r]; m1[r] = d2; k1[r] = kx; }
                else if (d2 < m2[r]) { m2[r] = d2; }
            }
        }
    }

    #pragma unroll
    for (int mask = 1; mask <= 8; mask <<= 1) {
        #pragma unroll
        for (int r = 0; r < 4; ++r) {
            float om1 = __shfl_xor(m1[r], mask);
            int   ok1 = __shfl_xor(k1[r], mask);
            float om2 = __shfl_xor(m2[r], mask);
            bool better = (om1 < m1[r]) || (om1 == m1[r] && ok1 < k1[r]);
            float nm2 = better ? fminf(m1[r], om2) : fminf(om1, m2[r]);
            if (better) { m1[r] = om1; k1[r] = ok1; }
            m2[r] = nm2;
        }
    }
    #pragma unroll
    for (int r = 0; r < 4; ++r) {
        int t = w * 16 + (lane >> 4) * 4 + r;
        int n = n0 + t;
        if ((lane & 15) == 0) {
            out[2 * NN * DN + s * NN + n] = (float)k1[r];
            if (m2[r] - m1[r] < REPAIR_THR) {
                int idx = atomicAdd((int*)ws, 1);
                if (idx < entcap) ((int*)ws)[WS_ENT + idx] = (s << 14) | n;
            }
        }
        int kb = __shfl(k1[r], lane & 48);
        float4 eg = Eg4[(s * KN + kb) * 16 + (lane & 15)];
        float* q = out + (size_t)n * DN + (lane & 15) * 4;
        atomicAdd(q + 0, eg.x); atomicAdd(q + 1, eg.y);
        atomicAdd(q + 2, eg.z); atomicAdd(q + 3, eg.w);
    }
}

// ------------------------------------------------------------- reduce -------
// ze = sum_s zpart[s]; zq = sum_s E[s, k1[s,n]].  One thread per (n, d4).
__global__ void reduce_kernel(const float* __restrict__ E, const float* __restrict__ ws,
                              float* __restrict__ out) {
    int idx = blockIdx.x * 256 + threadIdx.x;     // NN*16 = 262144
    int n = idx >> 4, c = idx & 15;
    const float4* zp4 = (const float4*)(ws + WS_ZP);
    float4 ze = make_float4(0.f, 0.f, 0.f, 0.f);
    #pragma unroll
    for (int s = 0; s < SN; ++s) {
        float4 v = zp4[((size_t)s * NN + n) * 16 + c];
        ze.x += v.x; ze.y += v.y; ze.z += v.z; ze.w += v.w;
    }
    ((float4*)out)[NN * 16 + (size_t)n * 16 + c] = ze;

    float4 zq = make_float4(0.f, 0.f, 0.f, 0.f);
    #pragma unroll
    for (int s = 0; s < SN; ++s) {
        int k = (int)(out[2 * NN * DN + s * NN + n] + 0.5f);
        float4 e = ((const float4*)E)[((size_t)s * KN + k) * 16 + c];
        zq.x += e.x; zq.y += e.y; zq.z += e.z; zq.w += e.w;
    }
    ((float4*)out)[(size_t)n * 16 + c] = zq;
}

// ---------------------------------------------------------------- repair ----
// Exact fp64 recompute for flagged near-tie positions; patches z_k and z_q.
// 4-way ILP on the dependent fp64 chains.
__global__ void repair_kernel(const float* __restrict__ x, const float* __restrict__ W,
                              const float* __restrict__ b, const float* __restrict__ gamma,
                              const float* __restrict__ beta, const float* __restrict__ bmean,
                              const float* __restrict__ bvar, const float* __restrict__ E,
                              float* __restrict__ ws, float* __restrict__ out, int entcap) {
    __shared__ double zd[64];
    __shared__ double red[256];
    __shared__ int redk[256];
    __shared__ double zzsh;
    __shared__ int shk[2];
    int cnt = ((int*)ws)[0]; if (cnt > entcap) cnt = entcap;
    const int tid = threadIdx.x;
    for (int idx = blockIdx.x; idx < cnt; idx += gridDim.x) {
        int code = ((int*)ws)[WS_ENT + idx];
        int s = code >> 14, n = code & (NN - 1);
        int e = tid & 63, q = tid >> 6;
        const float* xrow = x + (size_t)n * 64;
        double p0 = 0.0, p1 = 0.0, p2 = 0.0, p3 = 0.0;
        for (int d = q * 16; d < q * 16 + 16; d += 4) {
            p0 = fma((double)xrow[d],     (double)W[((size_t)s * 64 + d) * 64 + e],     p0);
            p1 = fma((double)xrow[d + 1], (double)W[((size_t)s * 64 + d + 1) * 64 + e], p1);
            p2 = fma((double)xrow[d + 2], (double)W[((size_t)s * 64 + d + 2) * 64 + e], p2);
            p3 = fma((double)xrow[d + 3], (double)W[((size_t)s * 64 + d + 3) * 64 + e], p3);
        }
        red[tid] = (p0 + p1) + (p2 + p3);
        __syncthreads();
        if (tid < 64) {
            double proj = (red[tid] + red[tid + 64]) + (red[tid + 128] + red[tid + 192]);
            double inv = 1.0 / sqrt((double)bvar[s * 64 + e] + 0.001);
            double bn = (double)gamma[s * 64 + e] * ((proj + (double)b[s * 64 + e]) - (double)bmean[s * 64 + e]) * inv
                      + (double)beta[s * 64 + e];
            double m = bn;
            #pragma unroll
            for (int mask = 1; mask <= 32; mask <<= 1) m = fmax(m, __shfl_xor(m, mask));
            double ex = exp(bn - m);
            double sm = ex;
            #pragma unroll
            for (int mask = 1; mask <= 32; mask <<= 1) sm += __shfl_xor(sm, mask);
            double z = (double)xrow[e] * (ex / sm);
            zd[e] = z;
            double zz = z * z;
            #pragma unroll
            for (int mask = 1; mask <= 32; mask <<= 1) zz += __shfl_xor(zz, mask);
            if (tid == 0) zzsh = zz;
        }
        __syncthreads();
        double bv = DBL_MAX; int bk = 1 << 30;
        for (int k = tid; k < KN; k += 256) {
            const float* er = E + ((size_t)s * KN + k) * 64;
            double d0 = 0.0, d1 = 0.0, d2a = 0.0, d3 = 0.0;
            double f0 = 0.0, f1 = 0.0, f2 = 0.0, f3 = 0.0;
            for (int d = 0; d < 64; d += 4) {
                double e0 = (double)er[d], e1 = (double)er[d + 1];
                double e2d = (double)er[d + 2], e3d = (double)er[d + 3];
                d0 = fma(zd[d], e0, d0);     d1 = fma(zd[d + 1], e1, d1);
                d2a = fma(zd[d + 2], e2d, d2a); d3 = fma(zd[d + 3], e3d, d3);
                f0 = fma(e0, e0, f0); f1 = fma(e1, e1, f1);
                f2 = fma(e2d, e2d, f2); f3 = fma(e3d, e3d, f3);
            }
            double dot = (d0 + d1) + (d2a + d3);
            double e2t = (f0 + f1) + (f2 + f3);
            double d2v = (zzsh - 2.0 * dot) + e2t;
            if (d2v < bv) { bv = d2v; bk = k; }
        }
        #pragma unroll
        for (int mask = 1; mask <= 32; mask <<= 1) {   // wave lex-min
            double ov = __shfl_xor(bv, mask);
            int   ok = __shfl_xor(bk, mask);
            if (ov < bv || (ov == bv && ok < bk)) { bv = ov; bk = ok; }
        }
        if ((tid & 63) == 0) { red[tid >> 6] = bv; redk[tid >> 6] = bk; }
        __syncthreads();
        if (tid == 0) {
            double m = red[0]; int mk = redk[0];
            for (int i = 1; i < 4; ++i)
                if (red[i] < m || (red[i] == m && redk[i] < mk)) { m = red[i]; mk = redk[i]; }
            int kold = (int)(out[2 * NN * 64 + s * NN + n] + 0.5f);
            shk[0] = mk; shk[1] = kold;
            out[2 * NN * 64 + s * NN + n] = (float)mk;
        }
        __syncthreads();
        int mk = shk[0], kold = shk[1];
        if (mk != kold && tid < 64)
            atomicAdd(out + n * 64 + tid, E[((size_t)s * KN + mk) * 64 + tid] - E[((size_t)s * KN + kold) * 64 + tid]);
        __syncthreads();
    }
}

// ---------------------------------------------------------------- launch ----
extern "C" void kernel_launch(void* const* d_in, const int* in_sizes, int n_in,
                              void* d_out, int out_size, void* d_ws, size_t ws_size,
                              hipStream_t stream) {
    const float* x     = (const float*)d_in[0];
    const float* W     = (const float*)d_in[1];
    const float* b     = (const float*)d_in[2];
    const float* gamma = (const float*)d_in[3];
    const float* beta  = (const float*)d_in[4];
    const float* bmean = (const float*)d_in[5];
    const float* bvar  = (const float*)d_in[6];
    const float* E     = (const float*)d_in[7];
    float* out = (float*)d_out;
    float* ws  = (float*)d_ws;

    bool staged = ws_size >= (size_t)WS_END * 4;

    long avail = (long)(ws_size / 4) - WS_ENT - 16;
    if (avail < 0) avail = 0;
    int entcap = (int)(avail > MAXFLAG ? MAXFLAG : avail);
    if (staged) entcap = MAXFLAG;

    if (staged) {
        prep_all_kernel<<<282, 256, 0, stream>>>(b, gamma, beta, bmean, bvar, W, E, ws);
        dim3 grid(128, 8);
        main_kernel<<<grid, 512, LDS_TOTAL, stream>>>(x, ws, out, entcap);
        reduce_kernel<<<1024, 256, 0, stream>>>(E, ws, out);
    } else {
        hipMemsetAsync(d_ws, 0, 64, stream);
        prep_kernel<<<18, 256, 0, stream>>>(b, gamma, beta, bmean, bvar, E, ws);
        hipMemsetAsync(d_out, 0, (size_t)(2 * NN * DN) * sizeof(float), stream);
        dim3 grid(256, 8);
        main_fb_kernel<<<grid, 256, FB_LDS_TOTAL, stream>>>(x, W, E, ws, out, entcap);
    }
    repair_kernel<<<2048, 256, 0, stream>>>(x, W, b, gamma, beta, bmean, bvar, E, ws, out, entcap);
}

// Round 10
// 150.127 us; speedup vs baseline: 1.7826x; 1.7826x over previous
//
#include <hip/hip_runtime.h>
#include <cfloat>
#include <cmath>

// Problem constants
#define SN 8
#define DN 64
#define KN 512
#define NN 16384            // B*T
#define CK 64               // K-chunk staged in LDS
#define REPAIR_THR 2e-3f    // float-path flag threshold (fallback kernel)
#define GAP_IK 4u           // packed-int flag: 4/4096 = 9.8e-4 in d2 units
#define MAXFLAG 32768

// workspace layout (float indices)
#define WS_CNT 0
#define WS_SCL 16
#define WS_OFF (16 + SN*DN)           // 528
#define WS_E2  (WS_OFF + SN*DN)       // 1040
#define WS_ENT (WS_E2 + SN*KN)        // 5136
#define WS_WTH (WS_ENT + MAXFLAG)     // 37904 : W^T hi bf16 image (SN*64*128 B, UNswizzled)
#define WS_WTL (WS_WTH + SN*64*32)    // 54288
#define WS_EH  (WS_WTL + SN*64*32)    // 70672 : E hi bf16 SWIZZLED image (SN*KN*128 B)
#define WS_EL  (WS_EH + SN*KN*32)     // 201744
#define WS_ZP  (WS_EL + SN*KN*32)     // 332816: z partials [S][N][D] fp32
#define WS_E2S (WS_ZP + SN*NN*DN)     // 8721424: 4096*||E||^2 (phase-D scaled)
#define WS_END (WS_E2S + SN*KN)       // 8725520 floats = 34.9 MB

// main LDS (512-thread / 128-row tile): Z hi 16K, Z lo 16K, E ping-pong 2x16K
#define LDS_ZH 0
#define LDS_ZL 16384
#define LDS_E0 32768
#define LDS_TOTAL 65536               // 2 blocks/CU = 16 waves/CU

// fallback (round-2 proven) LDS
#define FB_LDS_R2    17408
#define FB_LDS_TAIL  33792
#define FB_LDS_TOTAL 34816

typedef __attribute__((ext_vector_type(8))) short bf16x8;   // 8 bf16 = 4 VGPR
typedef __attribute__((ext_vector_type(4))) short s16x4;    // 8 B
typedef __attribute__((ext_vector_type(4))) float f32x4;    // MFMA acc

// float -> bf16(RTNE) hi + remainder
__device__ inline short bf_hi(float f, float& rem) {
    unsigned u = __float_as_uint(f);
    unsigned r = (u + 0x7fffu + ((u >> 16) & 1u)) & 0xffff0000u;
    rem = f - __uint_as_float(r);
    return (short)(r >> 16);
}
__device__ inline short bf_rn(float f) {
    unsigned u = __float_as_uint(f);
    return (short)((u + 0x7fffu + ((u >> 16) & 1u)) >> 16);
}
__device__ inline void cvt4(float a, float b, float c, float d, s16x4& h, s16x4& l) {
    float r0, r1, r2, r3;
    h.x = bf_hi(a, r0); h.y = bf_hi(b, r1); h.z = bf_hi(c, r2); h.w = bf_hi(d, r3);
    l.x = bf_rn(r0); l.y = bf_rn(r1); l.z = bf_rn(r2); l.w = bf_rn(r3);
}
__device__ inline float bf2f(unsigned short h) {
    return __uint_as_float(((unsigned)h) << 16);
}

union U8 { bf16x8 v; s16x4 q[2]; };

// ------------------------------------------------------------- prep_all -----
// One launch: blocks 0..255 E->hi/lo swizzled image; 256..263 W^T image;
// 264..281 E2 (raw + 4096-scaled), BN fold, and flag-counter zeroing.
__global__ void prep_all_kernel(const float* __restrict__ b, const float* __restrict__ gamma,
                                const float* __restrict__ beta, const float* __restrict__ bmean,
                                const float* __restrict__ bvar, const float* __restrict__ W,
                                const float* __restrict__ E, float* __restrict__ ws) {
    __shared__ float wt[64][65];
    const int blk = blockIdx.x, tid = threadIdx.x;
    if (blk < 256) {                           // E image (swizzled rows)
        int idx = blk * 256 + tid;             // SN*KN*16 = 65536
        int sk = idx >> 4, c4 = idx & 15;
        int k = sk & (KN - 1);
        float4 g = ((const float4*)E)[(size_t)sk * 16 + c4];
        s16x4 h4, l4;
        cvt4(g.x, g.y, g.z, g.w, h4, l4);
        size_t off = ((size_t)sk * 128 + c4 * 8) ^ ((k & 7) << 4);
        *(s16x4*)((char*)(ws + WS_EH) + off) = h4;
        *(s16x4*)((char*)(ws + WS_EL) + off) = l4;
    } else if (blk < 264) {                    // W^T image (UNswizzled)
        int s = blk - 256;
        #pragma unroll
        for (int r = 0; r < 4; ++r) {
            int i = r * 256 + tid;             // 1024 f4
            float4 g = ((const float4*)W)[(size_t)s * 1024 + i];
            int d = i >> 4, c4 = i & 15;
            wt[d][c4 * 4 + 0] = g.x; wt[d][c4 * 4 + 1] = g.y;
            wt[d][c4 * 4 + 2] = g.z; wt[d][c4 * 4 + 3] = g.w;
        }
        __syncthreads();
        #pragma unroll
        for (int r = 0; r < 4; ++r) {
            int j = r * 256 + tid;             // 64 e x 16 c4
            int e = j >> 4, c4 = j & 15;
            s16x4 h4, l4;
            cvt4(wt[c4 * 4 + 0][e], wt[c4 * 4 + 1][e], wt[c4 * 4 + 2][e], wt[c4 * 4 + 3][e], h4, l4);
            size_t off = (size_t)(s * 64 + e) * 128 + c4 * 8;
            *(s16x4*)((char*)(ws + WS_WTH) + off) = h4;
            *(s16x4*)((char*)(ws + WS_WTL) + off) = l4;
        }
    } else {                                   // E2 + BN fold + counter zero
        if (blk == 264 && tid < 16) ((int*)ws)[tid] = 0;
        int t2 = (blk - 264) * 256 + tid;
        if (t2 < SN * KN) {
            const float* er = E + (size_t)t2 * DN;
            double a = 0.0;
            for (int d = 0; d < DN; ++d) { double v = (double)er[d]; a = fma(v, v, a); }
            ws[WS_E2 + t2]  = (float)a;
            ws[WS_E2S + t2] = (float)(a * 4096.0);
        }
        int u = t2 - SN * KN;
        if (u >= 0 && u < SN * DN) {
            double inv = 1.0 / sqrt((double)bvar[u] + 0.001);
            double sc  = (double)gamma[u] * inv;
            ws[WS_SCL + u] = (float)sc;
            ws[WS_OFF + u] = (float)(((double)b[u] - (double)bmean[u]) * sc + (double)beta[u]);
        }
    }
}

// --------------------------------------------------- fallback-path prep -----
__global__ void prep_kernel(const float* __restrict__ b, const float* __restrict__ gamma,
                            const float* __restrict__ beta, const float* __restrict__ bmean,
                            const float* __restrict__ bvar, const float* __restrict__ E,
                            float* __restrict__ ws) {
    int tid = blockIdx.x * 256 + threadIdx.x;
    if (tid < SN * KN) {
        const float* er = E + (size_t)tid * DN;
        double a = 0.0;
        for (int d = 0; d < DN; ++d) { double v = (double)er[d]; a = fma(v, v, a); }
        ws[WS_E2 + tid] = (float)a;
    }
    int u = tid - SN * KN;
    if (u >= 0 && u < SN * DN) {
        double inv = 1.0 / sqrt((double)bvar[u] + 0.001);
        double sc  = (double)gamma[u] * inv;
        ws[WS_SCL + u] = (float)sc;
        ws[WS_OFF + u] = (float)(((double)b[u] - (double)bmean[u]) * sc + (double)beta[u]);
    }
}

// ---------------------------------------------------------------- main ------
// Round-8-proven structure: grid (128 tiles x 128 rows, 8 s), 512 threads
// (8 waves); wave w owns rows [16w,16w+16). x/W fragments register-direct;
// E chunks reg-prefetched into ping-pong LDS (1 barrier/chunk). z partials
// stored coalesced via LDS transpose. Argmin via packed u32 keys:
// key = (u32)((d2+16)*4096) << 9 | k.  + s_setprio around MFMA clusters.
__launch_bounds__(512, 4)
__global__ void main_kernel(const float* __restrict__ x, float* __restrict__ ws,
                            float* __restrict__ out, int entcap) {
    extern __shared__ char smraw[];
    const int tid = threadIdx.x;           // 0..511
    const int s  = blockIdx.y;
    const int n0 = blockIdx.x * 128;
    const int lane = tid & 63;
    const int w    = tid >> 6;             // 0..7
    const int cc   = lane & 15;
    const int kq   = lane >> 4;
    const int arow = w * 16 + cc;          // 0..127
    const int axor = (arow & 7) << 4;

    const char* eimg_h = (const char*)(ws + WS_EH) + (size_t)s * KN * 128;
    const char* eimg_l = (const char*)(ws + WS_EL) + (size_t)s * KN * 128;

    // prefetch E chunk 0 into regs (8K hi + 8K lo over 512 threads)
    float4 pf0 = *(const float4*)(eimg_h + tid * 16);
    float4 pf1 = *(const float4*)(eimg_l + tid * 16);

    // ---- A-fragments (x rows) built in registers ----
    U8 xah[2], xal[2];
    #pragma unroll
    for (int ks = 0; ks < 2; ++ks) {
        const float* xr = x + (size_t)(n0 + arow) * DN + ks * 32 + kq * 8;
        float4 a = *(const float4*)xr;
        float4 b2 = *(const float4*)(xr + 4);
        s16x4 h0, l0, h1, l1;
        cvt4(a.x, a.y, a.z, a.w, h0, l0);
        cvt4(b2.x, b2.y, b2.z, b2.w, h1, l1);
        xah[ks].q[0] = h0; xah[ks].q[1] = h1;
        xal[ks].q[0] = l0; xal[ks].q[1] = l1;
    }

    // ---- phase C: proj = x @ W via MFMA, W^T frags register-direct ----
    const char* wimg_h = (const char*)(ws + WS_WTH) + (size_t)s * 64 * 128;
    const char* wimg_l = (const char*)(ws + WS_WTL) + (size_t)s * 64 * 128;
    f32x4 pa[4];
    #pragma unroll
    for (int nt = 0; nt < 4; ++nt) pa[nt] = (f32x4){0.f, 0.f, 0.f, 0.f};
    #pragma unroll
    for (int ks = 0; ks < 2; ++ks) {
        #pragma unroll
        for (int nt = 0; nt < 4; ++nt) {
            int brow = nt * 16 + cc;
            bf16x8 bh = *(const bf16x8*)(wimg_h + brow * 128 + ks * 64 + kq * 16);
            bf16x8 bl = *(const bf16x8*)(wimg_l + brow * 128 + ks * 64 + kq * 16);
            pa[nt] = __builtin_amdgcn_mfma_f32_16x16x32_bf16(xah[ks].v, bh, pa[nt], 0, 0, 0);
            pa[nt] = __builtin_amdgcn_mfma_f32_16x16x32_bf16(xah[ks].v, bl, pa[nt], 0, 0, 0);
            pa[nt] = __builtin_amdgcn_mfma_f32_16x16x32_bf16(xal[ks].v, bh, pa[nt], 0, 0, 0);
        }
    }

    // ---- BN + softmax + z (C/D layout: e = nt*16+cc, row = w*16+kq*4+r) ----
    float sclv[4], oflv[4];
    #pragma unroll
    for (int nt = 0; nt < 4; ++nt) {
        sclv[nt] = ws[WS_SCL + s * 64 + nt * 16 + cc];
        oflv[nt] = ws[WS_OFF + s * 64 + nt * 16 + cc];
    }
    float zzq[4];                      // (zz + 16) * 4096 per owned row
    #pragma unroll
    for (int r = 0; r < 4; ++r) {
        int t = w * 16 + kq * 4 + r;
        float v0 = fmaf(pa[0][r], sclv[0], oflv[0]);
        float v1 = fmaf(pa[1][r], sclv[1], oflv[1]);
        float v2 = fmaf(pa[2][r], sclv[2], oflv[2]);
        float v3 = fmaf(pa[3][r], sclv[3], oflv[3]);
        float mx = fmaxf(fmaxf(v0, v1), fmaxf(v2, v3));
        mx = fmaxf(mx, __shfl_xor(mx, 1)); mx = fmaxf(mx, __shfl_xor(mx, 2));
        mx = fmaxf(mx, __shfl_xor(mx, 4)); mx = fmaxf(mx, __shfl_xor(mx, 8));
        float e0 = __expf(v0 - mx), e1 = __expf(v1 - mx);
        float e2v = __expf(v2 - mx), e3 = __expf(v3 - mx);
        float sm = e0 + e1 + e2v + e3;
        sm += __shfl_xor(sm, 1); sm += __shfl_xor(sm, 2);
        sm += __shfl_xor(sm, 4); sm += __shfl_xor(sm, 8);
        float inv = 1.0f / sm;
        float att[4] = { e0 * inv, e1 * inv, e2v * inv, e3 * inv };
        float zz = 0.f;
        int txor = (t & 7) << 4;
        #pragma unroll
        for (int nt = 0; nt < 4; ++nt) {
            int e = nt * 16 + cc;
            float xv = x[(size_t)(n0 + t) * DN + e];     // exact fp32 x
            float z = xv * att[nt];
            zz += z * z;
            float rem; short zh = bf_hi(z, rem); short zl = bf_rn(rem);
            int zoff = (t * 128 + e * 2) ^ txor;
            *(short*)(smraw + LDS_ZH + zoff) = zh;
            *(short*)(smraw + LDS_ZL + zoff) = zl;
        }
        zz += __shfl_xor(zz, 1); zz += __shfl_xor(zz, 2);
        zz += __shfl_xor(zz, 4); zz += __shfl_xor(zz, 8);
        zzq[r] = (zz + 16.f) * 4096.f;
    }

    // hoist z fragments (own rows, intra-wave LDS -> no barrier needed)
    bf16x8 zah[2], zal[2];
    #pragma unroll
    for (int ks = 0; ks < 2; ++ks) {
        int aoff = (arow * 128 + kq * 16 + ks * 64) ^ axor;
        zah[ks] = *(const bf16x8*)(smraw + LDS_ZH + aoff);
        zal[ks] = *(const bf16x8*)(smraw + LDS_ZL + aoff);
    }

    // stage chunk 0 into buffer 0; barrier also publishes Z block-wide
    {
        char* eb = smraw + LDS_E0;
        *(float4*)(eb + tid * 16) = pf0;
        *(float4*)(eb + 8192 + tid * 16) = pf1;
    }
    __syncthreads();

    // ---- ZP store: coalesced float4 via LDS transpose (z = hi + lo) ----
    #pragma unroll
    for (int j = 0; j < 4; ++j) {
        int a = tid + j * 512;             // 128 rows x 16 e-quads
        int t = a >> 4, q = a & 15;
        int off = (t * 128 + q * 8) ^ ((t & 7) << 4);
        s16x4 h = *(const s16x4*)(smraw + LDS_ZH + off);
        s16x4 l = *(const s16x4*)(smraw + LDS_ZL + off);
        float4 zv;
        zv.x = bf2f((unsigned short)h.x) + bf2f((unsigned short)l.x);
        zv.y = bf2f((unsigned short)h.y) + bf2f((unsigned short)l.y);
        zv.z = bf2f((unsigned short)h.z) + bf2f((unsigned short)l.z);
        zv.w = bf2f((unsigned short)h.w) + bf2f((unsigned short)l.w);
        ((float4*)(ws + WS_ZP))[((size_t)s * NN + n0 + t) * 16 + q] = zv;
    }

    // ---- phase D: z @ E^T via MFMA; ping-pong E, 1 barrier/chunk ----
    unsigned m1[4], m2[4];
    #pragma unroll
    for (int r = 0; r < 4; ++r) { m1[r] = 0xFFFFFFFFu; m2[r] = 0xFFFFFFFFu; }

    int p = 0;
    #pragma unroll 1
    for (int c = 0; c < KN / CK; ++c) {
        const char* ebuf = smraw + LDS_E0 + p * 16384;   // hi +0, lo +8192
        int kk = c * CK;
        if (c < KN / CK - 1) {                           // prefetch next chunk
            pf0 = *(const float4*)(eimg_h + (size_t)(kk + CK) * 128 + tid * 16);
            pf1 = *(const float4*)(eimg_l + (size_t)(kk + CK) * 128 + tid * 16);
        }
        float e2v[4];                                    // pre-scaled 4096*e2
        #pragma unroll
        for (int nt = 0; nt < 4; ++nt) e2v[nt] = ws[WS_E2S + s * KN + kk + nt * 16 + cc];

        f32x4 acc[4];
        #pragma unroll
        for (int nt = 0; nt < 4; ++nt) acc[nt] = (f32x4){0.f, 0.f, 0.f, 0.f};
        __builtin_amdgcn_s_setprio(1);
        #pragma unroll
        for (int ks = 0; ks < 2; ++ks) {
            #pragma unroll
            for (int nt = 0; nt < 4; ++nt) {
                int brow = nt * 16 + cc;
                int boff = (brow * 128 + kq * 16 + ks * 64) ^ ((brow & 7) << 4);
                bf16x8 bh = *(const bf16x8*)(ebuf + boff);
                bf16x8 bl = *(const bf16x8*)(ebuf + 8192 + boff);
                acc[nt] = __builtin_amdgcn_mfma_f32_16x16x32_bf16(zah[ks], bh, acc[nt], 0, 0, 0);
                acc[nt] = __builtin_amdgcn_mfma_f32_16x16x32_bf16(zah[ks], bl, acc[nt], 0, 0, 0);
                acc[nt] = __builtin_amdgcn_mfma_f32_16x16x32_bf16(zal[ks], bh, acc[nt], 0, 0, 0);
            }
        }
        __builtin_amdgcn_s_setprio(0);
        #pragma unroll
        for (int nt = 0; nt < 4; ++nt) {
            unsigned kx = (unsigned)(kk + nt * 16 + cc);
            #pragma unroll
            for (int r = 0; r < 4; ++r) {
                // cell = 4096*(d2+16) in [0, ~2^21) -> cvt exact, no clamp
                float cell = fmaf(-8192.f, acc[nt][r], zzq[r] + e2v[nt]);
                unsigned key = (((unsigned)cell) << 9) | kx;
                m2[r] = min(m2[r], max(m1[r], key));
                m1[r] = min(m1[r], key);
            }
        }
        if (c < KN / CK - 1) {
            char* nb = smraw + LDS_E0 + (p ^ 1) * 16384;
            *(float4*)(nb + tid * 16) = pf0;
            *(float4*)(nb + 8192 + tid * 16) = pf1;
            __syncthreads();                             // next buf published
            p ^= 1;
        }
    }

    // cross-lane (16 lanes = distinct k) merge; k-tiebreak free in key space
    #pragma unroll
    for (int mask = 1; mask <= 8; mask <<= 1) {
        #pragma unroll
        for (int r = 0; r < 4; ++r) {
            unsigned o1 = (unsigned)__shfl_xor((int)m1[r], mask);
            unsigned o2 = (unsigned)__shfl_xor((int)m2[r], mask);
            unsigned hi = max(m1[r], o1);
            m1[r] = min(m1[r], o1);
            m2[r] = min(min(m2[r], o2), hi);
        }
    }
    #pragma unroll
    for (int r = 0; r < 4; ++r) {
        int n = n0 + w * 16 + kq * 4 + r;
        if (cc == 0) {
            int k1 = (int)(m1[r] & 511u);
            out[2 * NN * DN + s * NN + n] = (float)k1;
            if ((m2[r] >> 9) - (m1[r] >> 9) <= GAP_IK) {   // near-tie -> fp64 repair
                int idx = atomicAdd((int*)ws, 1);
                if (idx < entcap) ((int*)ws)[WS_ENT + idx] = (s << 14) | n;
            }
        }
    }
}

// ----------------------------------------------------- fallback main --------
// Round-2-proven path for small workspaces: fp32 phase C, in-kernel E cvt,
// atomic zq/ze accumulation. Needs only WS_ENT region.
__launch_bounds__(256, 4)
__global__ void main_fb_kernel(const float* __restrict__ x, const float* __restrict__ W,
                               const float* __restrict__ E, float* __restrict__ ws,
                               float* __restrict__ out, int entcap) {
    extern __shared__ char smraw[];
    float4* xs4 = (float4*)smraw;
    float4* ws4 = (float4*)(smraw + FB_LDS_R2);
    char* ehb = smraw;
    char* elb = smraw + 8192;
    char* zhb = smraw + FB_LDS_R2;
    char* zlb = smraw + FB_LDS_R2 + 8192;
    float* tailf = (float*)(smraw + FB_LDS_TAIL);
    float* e2s = tailf; float* scl = tailf + 64; float* ofl = tailf + 128; float* zzs = tailf + 192;

    const int tid = threadIdx.x;
    const int tg = tid >> 4, lg = tid & 15;
    const int s  = blockIdx.y;
    const int n0 = blockIdx.x * 64;
    const float4* xg4 = (const float4*)x;
    const float4* Wg4 = (const float4*)W;
    const float4* Eg4 = (const float4*)E;

    #pragma unroll
    for (int r = 0; r < 4; ++r) {
        int i = r * 256 + tid;
        xs4[(i >> 4) * 17 + (i & 15)] = xg4[n0 * 16 + i];
        ws4[i] = Wg4[s * 1024 + i];
    }
    if (tid < 64) { scl[tid] = ws[WS_SCL + s * 64 + tid]; ofl[tid] = ws[WS_OFF + s * 64 + tid]; }
    __syncthreads();

    float pa[4][4];
    #pragma unroll
    for (int ti = 0; ti < 4; ++ti)
        #pragma unroll
        for (int j = 0; j < 4; ++j) pa[ti][j] = 0.f;
    #pragma unroll 4
    for (int c = 0; c < 16; ++c) {
        float4 xv[4], wv[4];
        #pragma unroll
        for (int ti = 0; ti < 4; ++ti) xv[ti] = xs4[(tg * 4 + ti) * 17 + c];
        #pragma unroll
        for (int dd = 0; dd < 4; ++dd) wv[dd] = ws4[(c * 4 + dd) * 16 + lg];
        #pragma unroll
        for (int ti = 0; ti < 4; ++ti) {
            float a0 = pa[ti][0], a1 = pa[ti][1], a2 = pa[ti][2], a3 = pa[ti][3];
            a0 = fmaf(xv[ti].x, wv[0].x, a0); a0 = fmaf(xv[ti].y, wv[1].x, a0);
            a0 = fmaf(xv[ti].z, wv[2].x, a0); a0 = fmaf(xv[ti].w, wv[3].x, a0);
            a1 = fmaf(xv[ti].x, wv[0].y, a1); a1 = fmaf(xv[ti].y, wv[1].y, a1);
            a1 = fmaf(xv[ti].z, wv[2].y, a1); a1 = fmaf(xv[ti].w, wv[3].y, a1);
            a2 = fmaf(xv[ti].x, wv[0].z, a2); a2 = fmaf(xv[ti].y, wv[1].z, a2);
            a2 = fmaf(xv[ti].z, wv[2].z, a2); a2 = fmaf(xv[ti].w, wv[3].z, a2);
            a3 = fmaf(xv[ti].x, wv[0].w, a3); a3 = fmaf(xv[ti].y, wv[1].w, a3);
            a3 = fmaf(xv[ti].z, wv[2].w, a3); a3 = fmaf(xv[ti].w, wv[3].w, a3);
            pa[ti][0] = a0; pa[ti][1] = a1; pa[ti][2] = a2; pa[ti][3] = a3;
        }
    }
    __syncthreads();

    {
        float s0 = scl[lg * 4 + 0], s1 = scl[lg * 4 + 1], s2 = scl[lg * 4 + 2], s3 = scl[lg * 4 + 3];
        float o0 = ofl[lg * 4 + 0], o1 = ofl[lg * 4 + 1], o2 = ofl[lg * 4 + 2], o3 = ofl[lg * 4 + 3];
        #pragma unroll
        for (int ti = 0; ti < 4; ++ti) {
            int t = tg * 4 + ti;
            float v0 = fmaf(pa[ti][0], s0, o0);
            float v1 = fmaf(pa[ti][1], s1, o1);
            float v2 = fmaf(pa[ti][2], s2, o2);
            float v3 = fmaf(pa[ti][3], s3, o3);
            float mx = fmaxf(fmaxf(v0, v1), fmaxf(v2, v3));
            mx = fmaxf(mx, __shfl_xor(mx, 1)); mx = fmaxf(mx, __shfl_xor(mx, 2));
            mx = fmaxf(mx, __shfl_xor(mx, 4)); mx = fmaxf(mx, __shfl_xor(mx, 8));
            float e0 = expf(v0 - mx), e1 = expf(v1 - mx), e2v = expf(v2 - mx), e3 = expf(v3 - mx);
            float sm = e0 + e1 + e2v + e3;
            sm += __shfl_xor(sm, 1); sm += __shfl_xor(sm, 2);
            sm += __shfl_xor(sm, 4); sm += __shfl_xor(sm, 8);
            float inv = 1.0f / sm;
            float4 xv = xs4[t * 17 + lg];
            float z0 = xv.x * (e0 * inv), z1 = xv.y * (e1 * inv);
            float z2 = xv.z * (e2v * inv), z3 = xv.w * (e3 * inv);
            float zz = z0 * z0 + z1 * z1 + z2 * z2 + z3 * z3;
            zz += __shfl_xor(zz, 1); zz += __shfl_xor(zz, 2);
            zz += __shfl_xor(zz, 4); zz += __shfl_xor(zz, 8);
            if (lg == 0) zzs[t] = zz;
            s16x4 h4, l4;
            cvt4(z0, z1, z2, z3, h4, l4);
            int zoff = (t * 128 + lg * 8) ^ ((t & 7) << 4);
            *(s16x4*)(zhb + zoff) = h4;
            *(s16x4*)(zlb + zoff) = l4;
            float* pz = out + NN * DN + (size_t)(n0 + t) * DN + lg * 4;
            atomicAdd(pz + 0, z0); atomicAdd(pz + 1, z1);
            atomicAdd(pz + 2, z2); atomicAdd(pz + 3, z3);
        }
    }
    __syncthreads();

    const int lane = tid & 63;
    const int w    = tid >> 6;
    const int arow = w * 16 + (lane & 15);
    const int kg16 = (lane >> 4) * 16;
    const int axor = (arow & 7) << 4;
    const int abase = arow * 128 + kg16;

    float zzv[4];
    #pragma unroll
    for (int r = 0; r < 4; ++r) zzv[r] = zzs[w * 16 + (lane >> 4) * 4 + r];

    float m1[4], m2[4]; int k1[4];
    #pragma unroll
    for (int r = 0; r < 4; ++r) { m1[r] = FLT_MAX; m2[r] = FLT_MAX; k1[r] = 0x7fffffff; }

    for (int kk = 0; kk < KN; kk += CK) {
        __syncthreads();
        #pragma unroll
        for (int r = 0; r < 4; ++r) {
            int i = r * 256 + tid;
            float4 g = Eg4[(s * KN + kk) * 16 + i];
            int row = i >> 4, c4 = i & 15;
            s16x4 h4, l4;
            cvt4(g.x, g.y, g.z, g.w, h4, l4);
            int off = (row * 128 + c4 * 8) ^ ((row & 7) << 4);
            *(s16x4*)(ehb + off) = h4;
            *(s16x4*)(elb + off) = l4;
        }
        if (tid < 64) e2s[tid] = ws[WS_E2 + s * KN + kk + tid];
        __syncthreads();

        f32x4 acc[4];
        #pragma unroll
        for (int nt = 0; nt < 4; ++nt) acc[nt] = (f32x4){0.f, 0.f, 0.f, 0.f};
        #pragma unroll
        for (int ks = 0; ks < 2; ++ks) {
            int aoff = (abase + ks * 64) ^ axor;
            bf16x8 ah = *(const bf16x8*)(zhb + aoff);
            bf16x8 al = *(const bf16x8*)(zlb + aoff);
            #pragma unroll
            for (int nt = 0; nt < 4; ++nt) {
                int brow = nt * 16 + (lane & 15);
                int boff = (brow * 128 + kg16 + ks * 64) ^ ((brow & 7) << 4);
                bf16x8 bh = *(const bf16x8*)(ehb + boff);
                bf16x8 bl = *(const bf16x8*)(elb + boff);
                acc[nt] = __builtin_amdgcn_mfma_f32_16x16x32_bf16(ah, bh, acc[nt], 0, 0, 0);
                acc[nt] = __builtin_amdgcn_mfma_f32_16x16x32_bf16(ah, bl, acc[nt], 0, 0, 0);
                acc[nt] = __builtin_amdgcn_mfma_f32_16x16x32_bf16(al, bh, acc[nt], 0, 0, 0);
            }
        }
        #pragma unroll
        for (int nt = 0; nt < 4; ++nt) {
            float e2v = e2s[nt * 16 + (lane & 15)];
            int kx = kk + nt * 16 + (lane & 15);
            #pragma unroll
            for (int r = 0; r < 4; ++r) {
                float d2 = fmaf(-2.0f, acc[nt][r], zzv[r]) + e2v;
                if (d2 < m1[r]) { m2[r] = m1[r]; m1[r] = d2; k1[r] = kx; }
                else if (d2 < m2[r]) { m2[r] = d2; }
            }
        }
    }

    #pragma unroll
    for (int mask = 1; mask <= 8; mask <<= 1) {
        #pragma unroll
        for (int r = 0; r < 4; ++r) {
            float om1 = __shfl_xor(m1[r], mask);
            int   ok1 = __shfl_xor(k1[r], mask);
            float om2 = __shfl_xor(m2[r], mask);
            bool better = (om1 < m1[r]) || (om1 == m1[r] && ok1 < k1[r]);
            float nm2 = better ? fminf(m1[r], om2) : fminf(om1, m2[r]);
            if (better) { m1[r] = om1; k1[r] = ok1; }
            m2[r] = nm2;
        }
    }
    #pragma unroll
    for (int r = 0; r < 4; ++r) {
        int t = w * 16 + (lane >> 4) * 4 + r;
        int n = n0 + t;
        if ((lane & 15) == 0) {
            out[2 * NN * DN + s * NN + n] = (float)k1[r];
            if (m2[r] - m1[r] < REPAIR_THR) {
                int idx = atomicAdd((int*)ws, 1);
                if (idx < entcap) ((int*)ws)[WS_ENT + idx] = (s << 14) | n;
            }
        }
        int kb = __shfl(k1[r], lane & 48);
        float4 eg = Eg4[(s * KN + kb) * 16 + (lane & 15)];
        float* q = out + (size_t)n * DN + (lane & 15) * 4;
        atomicAdd(q + 0, eg.x); atomicAdd(q + 1, eg.y);
        atomicAdd(q + 2, eg.z); atomicAdd(q + 3, eg.w);
    }
}

// ------------------------------------------------------------- reduce -------
// ze = sum_s zpart[s]; zq = sum_s E[s, k1[s,n]] using FINAL (repaired) k1.
__global__ void reduce_kernel(const float* __restrict__ E, const float* __restrict__ ws,
                              float* __restrict__ out) {
    int idx = blockIdx.x * 256 + threadIdx.x;     // NN*16 = 262144
    int n = idx >> 4, c = idx & 15;
    const float4* zp4 = (const float4*)(ws + WS_ZP);
    float4 ze = make_float4(0.f, 0.f, 0.f, 0.f);
    #pragma unroll
    for (int s = 0; s < SN; ++s) {
        float4 v = zp4[((size_t)s * NN + n) * 16 + c];
        ze.x += v.x; ze.y += v.y; ze.z += v.z; ze.w += v.w;
    }
    ((float4*)out)[NN * 16 + (size_t)n * 16 + c] = ze;

    float4 zq = make_float4(0.f, 0.f, 0.f, 0.f);
    #pragma unroll
    for (int s = 0; s < SN; ++s) {
        int k = (int)(out[2 * NN * DN + s * NN + n] + 0.5f);
        float4 e = ((const float4*)E)[((size_t)s * KN + k) * 16 + c];
        zq.x += e.x; zq.y += e.y; zq.z += e.z; zq.w += e.w;
    }
    ((float4*)out)[(size_t)n * 16 + c] = zq;
}

// ---------------------------------------------------------------- repair ----
// Exact fp64 recompute for flagged near-tie positions; fixes z_k. When
// do_patch==0 (staged path) it runs BEFORE reduce, so only k1 is written;
// when do_patch==1 (fallback) it also patches the already-accumulated zq.
__global__ void repair_kernel(const float* __restrict__ x, const float* __restrict__ W,
                              const float* __restrict__ b, const float* __restrict__ gamma,
                              const float* __restrict__ beta, const float* __restrict__ bmean,
                              const float* __restrict__ bvar, const float* __restrict__ E,
                              float* __restrict__ ws, float* __restrict__ out, int entcap,
                              int do_patch) {
    __shared__ double zd[64];
    __shared__ double red[256];
    __shared__ int redk[256];
    __shared__ double zzsh;
    __shared__ int shk[2];
    int cnt = ((int*)ws)[0]; if (cnt > entcap) cnt = entcap;
    const int tid = threadIdx.x;
    for (int idx = blockIdx.x; idx < cnt; idx += gridDim.x) {
        int code = ((int*)ws)[WS_ENT + idx];
        int s = code >> 14, n = code & (NN - 1);
        int e = tid & 63, q = tid >> 6;
        const float* xrow = x + (size_t)n * 64;
        double p0 = 0.0, p1 = 0.0, p2 = 0.0, p3 = 0.0;
        for (int d = q * 16; d < q * 16 + 16; d += 4) {
            p0 = fma((double)xrow[d],     (double)W[((size_t)s * 64 + d) * 64 + e],     p0);
            p1 = fma((double)xrow[d + 1], (double)W[((size_t)s * 64 + d + 1) * 64 + e], p1);
            p2 = fma((double)xrow[d + 2], (double)W[((size_t)s * 64 + d + 2) * 64 + e], p2);
            p3 = fma((double)xrow[d + 3], (double)W[((size_t)s * 64 + d + 3) * 64 + e], p3);
        }
        red[tid] = (p0 + p1) + (p2 + p3);
        __syncthreads();
        if (tid < 64) {
            double proj = (red[tid] + red[tid + 64]) + (red[tid + 128] + red[tid + 192]);
            double inv = 1.0 / sqrt((double)bvar[s * 64 + e] + 0.001);
            double bn = (double)gamma[s * 64 + e] * ((proj + (double)b[s * 64 + e]) - (double)bmean[s * 64 + e]) * inv
                      + (double)beta[s * 64 + e];
            double m = bn;
            #pragma unroll
            for (int mask = 1; mask <= 32; mask <<= 1) m = fmax(m, __shfl_xor(m, mask));
            double ex = exp(bn - m);
            double sm = ex;
            #pragma unroll
            for (int mask = 1; mask <= 32; mask <<= 1) sm += __shfl_xor(sm, mask);
            double z = (double)xrow[e] * (ex / sm);
            zd[e] = z;
            double zz = z * z;
            #pragma unroll
            for (int mask = 1; mask <= 32; mask <<= 1) zz += __shfl_xor(zz, mask);
            if (tid == 0) zzsh = zz;
        }
        __syncthreads();
        double bv = DBL_MAX; int bk = 1 << 30;
        for (int k = tid; k < KN; k += 256) {
            const float* er = E + ((size_t)s * KN + k) * 64;
            double d0 = 0.0, d1 = 0.0, d2a = 0.0, d3 = 0.0;
            double f0 = 0.0, f1 = 0.0, f2 = 0.0, f3 = 0.0;
            for (int d = 0; d < 64; d += 4) {
                double e0 = (double)er[d], e1 = (double)er[d + 1];
                double e2d = (double)er[d + 2], e3d = (double)er[d + 3];
                d0 = fma(zd[d], e0, d0);     d1 = fma(zd[d + 1], e1, d1);
                d2a = fma(zd[d + 2], e2d, d2a); d3 = fma(zd[d + 3], e3d, d3);
                f0 = fma(e0, e0, f0); f1 = fma(e1, e1, f1);
                f2 = fma(e2d, e2d, f2); f3 = fma(e3d, e3d, f3);
            }
            double dot = (d0 + d1) + (d2a + d3);
            double e2t = (f0 + f1) + (f2 + f3);
            double d2v = (zzsh - 2.0 * dot) + e2t;
            if (d2v < bv) { bv = d2v; bk = k; }
        }
        #pragma unroll
        for (int mask = 1; mask <= 32; mask <<= 1) {   // wave lex-min
            double ov = __shfl_xor(bv, mask);
            int   ok = __shfl_xor(bk, mask);
            if (ov < bv || (ov == bv && ok < bk)) { bv = ov; bk = ok; }
        }
        if ((tid & 63) == 0) { red[tid >> 6] = bv; redk[tid >> 6] = bk; }
        __syncthreads();
        if (tid == 0) {
            double m = red[0]; int mk = redk[0];
            for (int i = 1; i < 4; ++i)
                if (red[i] < m || (red[i] == m && redk[i] < mk)) { m = red[i]; mk = redk[i]; }
            int kold = (int)(out[2 * NN * 64 + s * NN + n] + 0.5f);
            shk[0] = mk; shk[1] = kold;
            out[2 * NN * 64 + s * NN + n] = (float)mk;
        }
        __syncthreads();
        if (do_patch) {
            int mk = shk[0], kold = shk[1];
            if (mk != kold && tid < 64)
                atomicAdd(out + n * 64 + tid, E[((size_t)s * KN + mk) * 64 + tid] - E[((size_t)s * KN + kold) * 64 + tid]);
        }
        __syncthreads();
    }
}

// ---------------------------------------------------------------- launch ----
extern "C" void kernel_launch(void* const* d_in, const int* in_sizes, int n_in,
                              void* d_out, int out_size, void* d_ws, size_t ws_size,
                              hipStream_t stream) {
    const float* x     = (const float*)d_in[0];
    const float* W     = (const float*)d_in[1];
    const float* b     = (const float*)d_in[2];
    const float* gamma = (const float*)d_in[3];
    const float* beta  = (const float*)d_in[4];
    const float* bmean = (const float*)d_in[5];
    const float* bvar  = (const float*)d_in[6];
    const float* E     = (const float*)d_in[7];
    float* out = (float*)d_out;
    float* ws  = (float*)d_ws;

    bool staged = ws_size >= (size_t)WS_END * 4;

    long avail = (long)(ws_size / 4) - WS_ENT - 16;
    if (avail < 0) avail = 0;
    int entcap = (int)(avail > MAXFLAG ? MAXFLAG : avail);
    if (staged) entcap = MAXFLAG;

    if (staged) {
        hipFuncSetAttribute((const void*)main_kernel, hipFuncAttributeMaxDynamicSharedMemorySize, LDS_TOTAL);
        prep_all_kernel<<<282, 256, 0, stream>>>(b, gamma, beta, bmean, bvar, W, E, ws);
        dim3 grid(128, 8);
        main_kernel<<<grid, 512, LDS_TOTAL, stream>>>(x, ws, out, entcap);
        // repair BEFORE reduce: fixes z_k only; reduce gathers with final k1.
        repair_kernel<<<2048, 256, 0, stream>>>(x, W, b, gamma, beta, bmean, bvar, E, ws, out, entcap, 0);
        reduce_kernel<<<1024, 256, 0, stream>>>(E, ws, out);
    } else {
        hipMemsetAsync(d_ws, 0, 64, stream);
        prep_kernel<<<18, 256, 0, stream>>>(b, gamma, beta, bmean, bvar, E, ws);
        hipMemsetAsync(d_out, 0, (size_t)(2 * NN * DN) * sizeof(float), stream);
        dim3 grid(256, 8);
        main_fb_kernel<<<grid, 256, FB_LDS_TOTAL, stream>>>(x, W, E, ws, out, entcap);
        repair_kernel<<<2048, 256, 0, stream>>>(x, W, b, gamma, beta, bmean, bvar, E, ws, out, entcap, 1);
    }
}